// Round 1
// baseline (11119.107 us; speedup 1.0000x reference)
//
#include <hip/hip_runtime.h>

#define N_ 2048
#define T_ 512
#define B_ 32
#define NWG 64            // 64 blocks, 1 per CU -> always co-resident (256 CUs)
#define NS 32
#define DT_ 1e-4f
#define U_CONST_ 0.3f
#define TAU_F_ 1.5f
#define TAU_D_ 0.3f
#define ALPHA_ 1.5f
#define I_B_ 8.0f
#define J_EI_ 1.1f
#define J_IE_ 2.2f
#define INV_TAU 125.0f          // 1/0.008
#define INV_ALPHA (1.0f/1.5f)
#define LO_SCALE 4096.0f        // 2^12: keeps lo parts out of fp16 denormal range
#define INV_LO_SCALE 2.44140625e-4f

// d_out float offsets: all_h, all_u, all_x, all_hI, outputs
#define U_OFF  (512ull*32*2048)
#define X_OFF  (2ull*512*32*2048)
#define HI_OFF (3ull*512*32*2048)
#define OUT_OFF (HI_OFF + 512ull*32)

typedef _Float16 half8 __attribute__((ext_vector_type(8)));
typedef float f32x4 __attribute__((ext_vector_type(4)));
typedef float f32x2 __attribute__((ext_vector_type(2)));
typedef unsigned long long u64;
typedef u64 u64x2 __attribute__((ext_vector_type(2)));

// Cross-WG shared state. NEW COHERENCE MODEL (r4): plain cached loads/stores,
// made coherent by one agent-scope release fence (buffer_wbl2) on the producer
// side before the flag store, and one agent-scope acquire fence (buffer_inv)
// on the consumer side after the flag is observed. This removes the per-load
// MALL round trip of the old sc0/sc1 system-scope atomics and lets the 8 WGs
// per XCD share L2 fills of v (8x less MALL read traffic).
__device__ __align__(16) u64 g_vh[2][(B_*N_)/4];    // v hi-halves, [b][n] packed 4/qword
__device__ __align__(16) u64 g_vl[2][(B_*N_)/4];    // v lo-halves (pre-scaled by 2^12)
__device__ float g_rp[2][B_*NWG];       // R partial sums, [b][wg]
__device__ unsigned g_flags[NWG*16];    // per-WG epoch flag, 64B apart

// flags stay system-scope atomics (MALL-coherent, proven path)
#define SYS_LD_U32(p)   __hip_atomic_load((p), __ATOMIC_RELAXED, __HIP_MEMORY_SCOPE_SYSTEM)
#define SYS_ST_U32(p,v) __hip_atomic_store((p), (v), __ATOMIC_RELAXED, __HIP_MEMORY_SCOPE_SYSTEM)

__device__ inline float rate_f(float h) {
  float z = h * INV_ALPHA;
  return ALPHA_ * (fmaxf(z, 0.0f) + log1pf(expf(-fabsf(z))));
}

// flags are monotonic within a launch; must start at 0 each launch
__global__ void init_kernel() {
  g_flags[threadIdx.x] = 0u;      // 1024 threads == NWG*16 entries
}

__global__ __launch_bounds__(256, 1) void stp_kernel(
    const float* __restrict__ inp, const float* __restrict__ W_in,
    const float* __restrict__ J, float* __restrict__ out)
{
  const int tid  = threadIdx.x;
  const int wg   = blockIdx.x;
  const int wave = tid >> 6;
  const int lane = tid & 63;

  __shared__ float sh_C[4][1024];
  __shared__ float sh_part[256];         // [gc(8)][b(32)]
  __shared__ float sh_hI[32], sh_RI[32], sh_inp[32];

  // ---- J slice -> registers as split fp16 B-fragments ----
  half8 jh[2][16], jl[2][16];
  {
    const int r = lane & 15, q = lane >> 4;
    #pragma unroll
    for (int nt = 0; nt < 2; ++nt)
      #pragma unroll
      for (int c = 0; c < 16; ++c) {
        const float* src = J + (size_t)(wg*NS + nt*16 + r) * N_ + wave*512 + c*32 + q*8;
        half8 hv, lv;
        #pragma unroll
        for (int j = 0; j < 8; ++j) {
          float f = src[j];
          _Float16 hi = (_Float16)f;
          _Float16 lo = (_Float16)((f - (float)hi) * LO_SCALE);
          hv[j] = hi; lv[j] = lo;
        }
        jh[nt][c] = hv; jl[nt][c] = lv;
      }
  }

  // thread -> (2 adjacent neurons) x (2 batches); state lives in registers
  const int np = tid & 15;               // neuron-pair index within WG
  const int n0 = wg*NS + 2*np;           // global neuron (even)
  const int bq = tid >> 4;               // batch 0..15 (+16 for c=1)
  const float w0 = W_in[n0], w1 = W_in[n0+1];

  float hh[2][2], uu[2][2], xx[2][2];
  #pragma unroll
  for (int c = 0; c < 2; ++c)
    #pragma unroll
    for (int j = 0; j < 2; ++j) { hh[c][j] = 0.0f; uu[c][j] = U_CONST_; xx[c][j] = 1.0f; }

  if (tid < 32) sh_hI[tid] = 0.0f;
  __syncthreads();

  for (int t = 0; t < T_; ++t) {
    const int pb = t & 1;
    unsigned* vhd = (unsigned*)g_vh[pb];
    unsigned* vld = (unsigned*)g_vl[pb];

    // ---- phase A: R, v (split fp16, PLAIN cached stores), u/x update, R-partials ----
    #pragma unroll
    for (int c = 0; c < 2; ++c) {
      const int b = bq + 16*c;
      float R0 = rate_f(hh[c][0]), R1 = rate_f(hh[c][1]);
      float v0 = uu[c][0]*xx[c][0]*R0, v1 = uu[c][1]*xx[c][1]*R1;
      _Float16 h0 = (_Float16)v0, h1 = (_Float16)v1;
      _Float16 l0 = (_Float16)((v0 - (float)h0) * LO_SCALE);
      _Float16 l1 = (_Float16)((v1 - (float)h1) * LO_SCALE);
      unsigned hp = (unsigned)__builtin_bit_cast(unsigned short, h0)
                  | ((unsigned)__builtin_bit_cast(unsigned short, h1) << 16);
      unsigned lp = (unsigned)__builtin_bit_cast(unsigned short, l0)
                  | ((unsigned)__builtin_bit_cast(unsigned short, l1) << 16);
      const unsigned idx = (unsigned)(b*N_ + n0) >> 1;
      vhd[idx] = hp;                      // plain store -> L2 (flushed by wbl2 below)
      vld[idx] = lp;
      uu[c][0] += ((U_CONST_-uu[c][0])*(1.0f/TAU_F_) + U_CONST_*(1.0f-uu[c][0])*R0)*DT_;
      uu[c][1] += ((U_CONST_-uu[c][1])*(1.0f/TAU_F_) + U_CONST_*(1.0f-uu[c][1])*R1)*DT_;
      xx[c][0] += ((1.0f-xx[c][0])*(1.0f/TAU_D_) - v0)*DT_;
      xx[c][1] += ((1.0f-xx[c][1])*(1.0f/TAU_D_) - v1)*DT_;
      // WG-complete R sum for batch b lives in this 16-lane group
      float s = R0 + R1;
      s += __shfl_xor(s, 1); s += __shfl_xor(s, 2);
      s += __shfl_xor(s, 4); s += __shfl_xor(s, 8);
      if ((lane & 15) == 0) g_rp[pb][b*NWG + wg] = s;   // plain store
    }

    // ---- device barrier: arrive ----
    __syncthreads();                     // per-wave vmcnt(0): all stores are in L2
    if (tid == 0) {
      // flush this XCD's L2 to the MALL, then publish the epoch
      __builtin_amdgcn_fence(__ATOMIC_RELEASE, "agent");   // buffer_wbl2 + waits
      SYS_ST_U32(&g_flags[wg*16], (unsigned)(t + 1));
    }

    // overlapped with barrier wait: output stores (nontemporal -> not in the
    // wbl2 writeback set; only read by out_kernel after this kernel ends)
    #pragma unroll
    for (int c = 0; c < 2; ++c) {
      const int b = bq + 16*c;
      const size_t o = (size_t)t*(B_*N_) + (size_t)b*N_ + n0;
      f32x2 uv = {uu[c][0], uu[c][1]};
      f32x2 xv = {xx[c][0], xx[c][1]};
      __builtin_nontemporal_store(uv, (f32x2*)&out[U_OFF + o]);
      __builtin_nontemporal_store(xv, (f32x2*)&out[X_OFF + o]);
    }
    if (tid < 32) sh_inp[tid] = inp[t*B_ + tid];

    // ---- device barrier: wait (wave0 polls 64 flags, one per lane) ----
    if (wave == 0) {
      const unsigned target = (unsigned)(t + 1);
      while (true) {
        unsigned f = SYS_LD_U32(&g_flags[lane*16]);
        if (__ballot(f >= target) == ~0ull) break;
        __builtin_amdgcn_s_sleep(1);
      }
    }
    __syncthreads();
    // invalidate L1+L2 so the plain loads below see every WG's flushed data
    __builtin_amdgcn_fence(__ATOMIC_ACQUIRE, "agent");     // buffer_inv

    // ---- R-partial gather (plain loads; 8 consecutive floats -> dwordx4) ----
    {
      const int b2 = tid & 31, gc = tid >> 5;
      float s = 0.0f;
      #pragma unroll
      for (int k = 0; k < 8; ++k)
        s += g_rp[pb][b2*NWG + gc*8 + k];
      sh_part[gc*32 + b2] = s;
    }

    // ---- phase C: split-fp16 MFMA over register-resident J ----
    // v loads are now plain global_load_dwordx4: deeply pipelined by the
    // scheduler, L2-shared across the 8 WGs of each XCD.
    {
      const int r = lane & 15, q = lane >> 4;
      const u64* vhp = g_vh[pb];
      const u64* vlp = g_vl[pb];
      f32x4 aH00 = {0,0,0,0}, aH01 = {0,0,0,0}, aH10 = {0,0,0,0}, aH11 = {0,0,0,0};
      f32x4 aL00 = {0,0,0,0}, aL01 = {0,0,0,0}, aL10 = {0,0,0,0}, aL11 = {0,0,0,0};
      const int base0 = (r*N_      + wave*512 + q*8) >> 2;   // qword index
      const int base1 = ((r+16)*N_ + wave*512 + q*8) >> 2;
      #pragma unroll
      for (int c = 0; c < 16; ++c) {
        const int o0 = base0 + c*8, o1 = base1 + c*8;
        u64x2 th0 = *(const u64x2*)(vhp + o0);
        u64x2 tl0 = *(const u64x2*)(vlp + o0);
        u64x2 th1 = *(const u64x2*)(vhp + o1);
        u64x2 tl1 = *(const u64x2*)(vlp + o1);
        half8 ah0 = __builtin_bit_cast(half8, th0);
        half8 al0 = __builtin_bit_cast(half8, tl0);
        half8 ah1 = __builtin_bit_cast(half8, th1);
        half8 al1 = __builtin_bit_cast(half8, tl1);
        aH00 = __builtin_amdgcn_mfma_f32_16x16x32_f16(ah0, jh[0][c], aH00, 0, 0, 0);
        aH01 = __builtin_amdgcn_mfma_f32_16x16x32_f16(ah0, jh[1][c], aH01, 0, 0, 0);
        aH10 = __builtin_amdgcn_mfma_f32_16x16x32_f16(ah1, jh[0][c], aH10, 0, 0, 0);
        aH11 = __builtin_amdgcn_mfma_f32_16x16x32_f16(ah1, jh[1][c], aH11, 0, 0, 0);
        aL00 = __builtin_amdgcn_mfma_f32_16x16x32_f16(ah0, jl[0][c], aL00, 0, 0, 0);
        aL00 = __builtin_amdgcn_mfma_f32_16x16x32_f16(al0, jh[0][c], aL00, 0, 0, 0);
        aL01 = __builtin_amdgcn_mfma_f32_16x16x32_f16(ah0, jl[1][c], aL01, 0, 0, 0);
        aL01 = __builtin_amdgcn_mfma_f32_16x16x32_f16(al0, jh[1][c], aL01, 0, 0, 0);
        aL10 = __builtin_amdgcn_mfma_f32_16x16x32_f16(ah1, jl[0][c], aL10, 0, 0, 0);
        aL10 = __builtin_amdgcn_mfma_f32_16x16x32_f16(al1, jh[0][c], aL10, 0, 0, 0);
        aL11 = __builtin_amdgcn_mfma_f32_16x16x32_f16(ah1, jl[1][c], aL11, 0, 0, 0);
        aL11 = __builtin_amdgcn_mfma_f32_16x16x32_f16(al1, jh[1][c], aL11, 0, 0, 0);
      }
      #pragma unroll
      for (int i = 0; i < 4; ++i) {
        int row = q*4 + i;                   // C/D: col=lane&15, row=quad*4+reg
        sh_C[wave][ row     *32      + r] = aH00[i] + INV_LO_SCALE*aL00[i];
        sh_C[wave][ row     *32 + 16 + r] = aH01[i] + INV_LO_SCALE*aL01[i];
        sh_C[wave][(row+16) *32      + r] = aH10[i] + INV_LO_SCALE*aL10[i];
        sh_C[wave][(row+16) *32 + 16 + r] = aH11[i] + INV_LO_SCALE*aL11[i];
      }
    }
    __syncthreads();

    // ---- h_I update (needs sh_part complete) ----
    if (tid < 32) {
      float s = 0.0f;
      #pragma unroll
      for (int gc = 0; gc < 8; ++gc) s += sh_part[gc*32 + tid];
      float hI = sh_hI[tid];
      sh_RI[tid] = rate_f(hI);               // pre-update R_I
      float hI2 = hI + DT_*INV_TAU*(-hI + J_IE_*s);
      sh_hI[tid] = hI2;
      if (wg == 0) __builtin_nontemporal_store(hI2, &out[HI_OFF + (size_t)t*B_ + tid]);
    }
    __syncthreads();

    // ---- phase D: h update (registers) + all_h store ----
    #pragma unroll
    for (int c = 0; c < 2; ++c) {
      const int b = bq + 16*c;
      const int e = b*32 + 2*np;
      float sy0 = sh_C[0][e]   + sh_C[1][e]   + sh_C[2][e]   + sh_C[3][e];
      float sy1 = sh_C[0][e+1] + sh_C[1][e+1] + sh_C[2][e+1] + sh_C[3][e+1];
      float ib = sh_inp[b];
      float ri = J_EI_*INV_TAU*sh_RI[b];
      float dh0 = (-hh[c][0] + sy0 + I_B_ + ib*w0)*INV_TAU - ri;
      float dh1 = (-hh[c][1] + sy1 + I_B_ + ib*w1)*INV_TAU - ri;
      hh[c][0] += dh0*DT_;
      hh[c][1] += dh1*DT_;
      f32x2 hv = {hh[c][0], hh[c][1]};
      __builtin_nontemporal_store(hv,
          (f32x2*)&out[(size_t)t*(B_*N_) + (size_t)b*N_ + n0]);
    }
    // next A reads only this thread's registers; shared buffers are re-written
    // only after the next barriers -> no extra __syncthreads needed here
  }
}

// outputs[t,b] = sum_n rate(all_h[t,b,n]) * W_out[n] — post-hoc, no atomics
__global__ __launch_bounds__(256) void out_kernel(
    const float* __restrict__ allh, const float* __restrict__ W_out,
    float* __restrict__ outp)
{
  const int bid = blockIdx.x;              // t*32 + b
  const int tid = threadIdx.x;
  __shared__ float red[4];
  const float* hrow = allh + (size_t)bid * N_;
  float s = 0.0f;
  #pragma unroll
  for (int i = 0; i < 8; ++i) {
    int n = tid + 256*i;
    s += rate_f(hrow[n]) * W_out[n];
  }
  s += __shfl_xor(s, 32); s += __shfl_xor(s, 16); s += __shfl_xor(s, 8);
  s += __shfl_xor(s, 4);  s += __shfl_xor(s, 2);  s += __shfl_xor(s, 1);
  if ((tid & 63) == 0) red[tid >> 6] = s;
  __syncthreads();
  if (tid == 0) outp[bid] = red[0] + red[1] + red[2] + red[3];
}

extern "C" void kernel_launch(void* const* d_in, const int* in_sizes, int n_in,
                              void* d_out, int out_size, void* d_ws, size_t ws_size,
                              hipStream_t stream)
{
  const float* inp   = (const float*)d_in[0];
  const float* W_in  = (const float*)d_in[1];
  const float* J     = (const float*)d_in[2];
  const float* W_out = (const float*)d_in[3];
  float* out = (float*)d_out;

  hipLaunchKernelGGL(init_kernel, dim3(1), dim3(NWG*16), 0, stream);
  hipLaunchKernelGGL(stp_kernel, dim3(NWG), dim3(256), 0, stream,
                     inp, W_in, J, out);
  hipLaunchKernelGGL(out_kernel, dim3(T_*B_), dim3(256), 0, stream,
                     out, W_out, out + OUT_OFF);
}

// Round 2
// 9883.910 us; speedup vs baseline: 1.1250x; 1.1250x over previous
//
#include <hip/hip_runtime.h>

#define N_ 2048
#define T_ 512
#define B_ 32
#define NWG 64            // 64 blocks, 1 per CU -> always co-resident (256 CUs)
#define NS 32
#define DT_ 1e-4f
#define U_CONST_ 0.3f
#define TAU_F_ 1.5f
#define TAU_D_ 0.3f
#define ALPHA_ 1.5f
#define I_B_ 8.0f
#define J_EI_ 1.1f
#define J_IE_ 2.2f
#define INV_TAU 125.0f          // 1/0.008
#define INV_ALPHA (1.0f/1.5f)
#define LO_SCALE 4096.0f        // 2^12: keeps lo parts out of fp16 denormal range
#define INV_LO_SCALE 2.44140625e-4f

// d_out float offsets: all_h, all_u, all_x, all_hI, outputs
#define U_OFF  (512ull*32*2048)
#define X_OFF  (2ull*512*32*2048)
#define HI_OFF (3ull*512*32*2048)
#define OUT_OFF (HI_OFF + 512ull*32)

typedef _Float16 half8 __attribute__((ext_vector_type(8)));
typedef float f32x4 __attribute__((ext_vector_type(4)));
typedef float f32x2 __attribute__((ext_vector_type(2)));
typedef unsigned long long u64;
typedef u64 u64x2 __attribute__((ext_vector_type(2)));

// Cross-WG shared state. Accessed ONLY with system-scope relaxed atomics
// (sc0 sc1 -> L1/L2 bypass, coherent at the MALL). r5 sync model: NO global
// barrier. c-iteration c of wave w consumes exactly producer WG 16w+c, so
// each wave waits on only its 16 producer flags (per-producer dataflow).
__device__ u64   g_vh[2][(B_*N_)/4];    // v hi-halves, [b][n] packed 4 per qword
__device__ u64   g_vl[2][(B_*N_)/4];    // v lo-halves (pre-scaled by 2^12)
__device__ float g_rp[2][B_*NWG];       // R partial sums, [b][wg]
__device__ unsigned g_flags[NWG*16];    // per-WG epoch flag, 64B apart

#define SYS_LD_U64(p)   __hip_atomic_load((p), __ATOMIC_RELAXED, __HIP_MEMORY_SCOPE_SYSTEM)
#define SYS_LD_F32(p)   __hip_atomic_load((p), __ATOMIC_RELAXED, __HIP_MEMORY_SCOPE_SYSTEM)
#define SYS_LD_U32(p)   __hip_atomic_load((p), __ATOMIC_RELAXED, __HIP_MEMORY_SCOPE_SYSTEM)
#define SYS_ST_U32(p,v) __hip_atomic_store((p), (v), __ATOMIC_RELAXED, __HIP_MEMORY_SCOPE_SYSTEM)
#define SYS_ST_F32(p,v) __hip_atomic_store((p), (v), __ATOMIC_RELAXED, __HIP_MEMORY_SCOPE_SYSTEM)

__device__ inline float rate_f(float h) {
  float z = h * INV_ALPHA;
  return ALPHA_ * (fmaxf(z, 0.0f) + log1pf(expf(-fabsf(z))));
}

// flags are monotonic within a launch; must start at 0 each launch
__global__ void init_kernel() {
  g_flags[threadIdx.x] = 0u;      // 1024 threads == NWG*16 entries
}

__global__ __launch_bounds__(256, 1) void stp_kernel(
    const float* __restrict__ inp, const float* __restrict__ W_in,
    const float* __restrict__ J, float* __restrict__ out)
{
  const int tid  = threadIdx.x;
  const int wg   = blockIdx.x;
  const int wave = tid >> 6;
  const int lane = tid & 63;

  __shared__ float sh_C[4][1024];
  __shared__ float sh_part[256];         // [gc(8)][b(32)]; gc = wave*2 + half
  __shared__ float sh_hI[32], sh_RI[32], sh_inp[32];

  // ---- J slice -> registers as split fp16 B-fragments ----
  half8 jh[2][16], jl[2][16];
  {
    const int r = lane & 15, q = lane >> 4;
    #pragma unroll
    for (int nt = 0; nt < 2; ++nt)
      #pragma unroll
      for (int c = 0; c < 16; ++c) {
        const float* src = J + (size_t)(wg*NS + nt*16 + r) * N_ + wave*512 + c*32 + q*8;
        half8 hv, lv;
        #pragma unroll
        for (int j = 0; j < 8; ++j) {
          float f = src[j];
          _Float16 hi = (_Float16)f;
          _Float16 lo = (_Float16)((f - (float)hi) * LO_SCALE);
          hv[j] = hi; lv[j] = lv[j] = lo;
        }
        jh[nt][c] = hv; jl[nt][c] = lv;
      }
  }

  // thread -> (2 adjacent neurons) x (2 batches); state lives in registers
  const int np = tid & 15;               // neuron-pair index within WG
  const int n0 = wg*NS + 2*np;           // global neuron (even)
  const int bq = tid >> 4;               // batch 0..15 (+16 for c=1)
  const float w0 = W_in[n0], w1 = W_in[n0+1];

  float hh[2][2], uu[2][2], xx[2][2];
  #pragma unroll
  for (int c = 0; c < 2; ++c)
    #pragma unroll
    for (int j = 0; j < 2; ++j) { hh[c][j] = 0.0f; uu[c][j] = U_CONST_; xx[c][j] = 1.0f; }

  if (tid < 32) sh_hI[tid] = 0.0f;
  __syncthreads();

  for (int t = 0; t < T_; ++t) {
    const int pb = t & 1;
    unsigned* vhd = (unsigned*)g_vh[pb];
    unsigned* vld = (unsigned*)g_vl[pb];

    // ---- phase A: R, v (split fp16, system-store), u/x reg update, R-partials ----
    #pragma unroll
    for (int c = 0; c < 2; ++c) {
      const int b = bq + 16*c;
      float R0 = rate_f(hh[c][0]), R1 = rate_f(hh[c][1]);
      float v0 = uu[c][0]*xx[c][0]*R0, v1 = uu[c][1]*xx[c][1]*R1;
      _Float16 h0 = (_Float16)v0, h1 = (_Float16)v1;
      _Float16 l0 = (_Float16)((v0 - (float)h0) * LO_SCALE);
      _Float16 l1 = (_Float16)((v1 - (float)h1) * LO_SCALE);
      unsigned hp = (unsigned)__builtin_bit_cast(unsigned short, h0)
                  | ((unsigned)__builtin_bit_cast(unsigned short, h1) << 16);
      unsigned lp = (unsigned)__builtin_bit_cast(unsigned short, l0)
                  | ((unsigned)__builtin_bit_cast(unsigned short, l1) << 16);
      const unsigned idx = (unsigned)(b*N_ + n0) >> 1;
      SYS_ST_U32(vhd + idx, hp);
      SYS_ST_U32(vld + idx, lp);
      uu[c][0] += ((U_CONST_-uu[c][0])*(1.0f/TAU_F_) + U_CONST_*(1.0f-uu[c][0])*R0)*DT_;
      uu[c][1] += ((U_CONST_-uu[c][1])*(1.0f/TAU_F_) + U_CONST_*(1.0f-uu[c][1])*R1)*DT_;
      xx[c][0] += ((1.0f-xx[c][0])*(1.0f/TAU_D_) - v0)*DT_;
      xx[c][1] += ((1.0f-xx[c][1])*(1.0f/TAU_D_) - v1)*DT_;
      // WG-complete R sum for batch b lives in this 16-lane group
      float s = R0 + R1;
      s += __shfl_xor(s, 1); s += __shfl_xor(s, 2);
      s += __shfl_xor(s, 4); s += __shfl_xor(s, 8);
      if ((lane & 15) == 0) SYS_ST_F32(&g_rp[pb][b*NWG + wg], s);
    }

    // ---- arrive: drain all waves' bypass stores, then publish epoch ----
    __syncthreads();                     // per-wave vmcnt(0): stores are at the MALL
    if (tid == 0) SYS_ST_U32(&g_flags[wg*16], (unsigned)(t + 1));

    // overlapped: output stores (nontemporal, never re-read by this kernel)
    #pragma unroll
    for (int c = 0; c < 2; ++c) {
      const int b = bq + 16*c;
      const size_t o = (size_t)t*(B_*N_) + (size_t)b*N_ + n0;
      f32x2 uv = {uu[c][0], uu[c][1]};
      f32x2 xv = {xx[c][0], xx[c][1]};
      __builtin_nontemporal_store(uv, (f32x2*)&out[U_OFF + o]);
      __builtin_nontemporal_store(xv, (f32x2*)&out[X_OFF + o]);
    }
    if (tid < 32) sh_inp[tid] = inp[t*B_ + tid];

    // ---- per-wave wait: only this wave's 16 producers (WGs 16*wave .. +15) ----
    {
      const unsigned target = (unsigned)(t + 1);
      const int p = wave*16 + (lane & 15);
      while (true) {
        unsigned f = SYS_LD_U32(&g_flags[p*16]);
        if (__ballot(f >= target) == ~0ull) break;
        __builtin_amdgcn_s_sleep(1);
      }
    }
    __atomic_signal_fence(__ATOMIC_ACQUIRE);

    // ---- per-wave R-partial gather (this wave's 16 producers only) ----
    {
      const int b2 = lane & 31, half = lane >> 5;
      float s = 0.0f;
      #pragma unroll
      for (int k = 0; k < 8; ++k)
        s += SYS_LD_F32(&g_rp[pb][b2*NWG + wave*16 + half*8 + k]);
      sh_part[(wave*2 + half)*32 + b2] = s;
    }

    // ---- phase C: split-fp16 MFMA over register-resident J ----
    {
      const int r = lane & 15, q = lane >> 4;
      f32x4 aH00 = {0,0,0,0}, aH01 = {0,0,0,0}, aH10 = {0,0,0,0}, aH11 = {0,0,0,0};
      f32x4 aL00 = {0,0,0,0}, aL01 = {0,0,0,0}, aL10 = {0,0,0,0}, aL11 = {0,0,0,0};
      const int base0 = (r*N_      + wave*512 + q*8) >> 2;   // qword index
      const int base1 = ((r+16)*N_ + wave*512 + q*8) >> 2;
      #pragma unroll
      for (int c = 0; c < 16; ++c) {
        const int o0 = base0 + c*8, o1 = base1 + c*8;
        u64x2 th0 = { SYS_LD_U64(&g_vh[pb][o0]), SYS_LD_U64(&g_vh[pb][o0+1]) };
        u64x2 tl0 = { SYS_LD_U64(&g_vl[pb][o0]), SYS_LD_U64(&g_vl[pb][o0+1]) };
        u64x2 th1 = { SYS_LD_U64(&g_vh[pb][o1]), SYS_LD_U64(&g_vh[pb][o1+1]) };
        u64x2 tl1 = { SYS_LD_U64(&g_vl[pb][o1]), SYS_LD_U64(&g_vl[pb][o1+1]) };
        half8 ah0 = __builtin_bit_cast(half8, th0);
        half8 al0 = __builtin_bit_cast(half8, tl0);
        half8 ah1 = __builtin_bit_cast(half8, th1);
        half8 al1 = __builtin_bit_cast(half8, tl1);
        aH00 = __builtin_amdgcn_mfma_f32_16x16x32_f16(ah0, jh[0][c], aH00, 0, 0, 0);
        aH01 = __builtin_amdgcn_mfma_f32_16x16x32_f16(ah0, jh[1][c], aH01, 0, 0, 0);
        aH10 = __builtin_amdgcn_mfma_f32_16x16x32_f16(ah1, jh[0][c], aH10, 0, 0, 0);
        aH11 = __builtin_amdgcn_mfma_f32_16x16x32_f16(ah1, jh[1][c], aH11, 0, 0, 0);
        aL00 = __builtin_amdgcn_mfma_f32_16x16x32_f16(ah0, jl[0][c], aL00, 0, 0, 0);
        aL00 = __builtin_amdgcn_mfma_f32_16x16x32_f16(al0, jh[0][c], aL00, 0, 0, 0);
        aL01 = __builtin_amdgcn_mfma_f32_16x16x32_f16(ah0, jl[1][c], aL01, 0, 0, 0);
        aL01 = __builtin_amdgcn_mfma_f32_16x16x32_f16(al0, jh[1][c], aL01, 0, 0, 0);
        aL10 = __builtin_amdgcn_mfma_f32_16x16x32_f16(ah1, jl[0][c], aL10, 0, 0, 0);
        aL10 = __builtin_amdgcn_mfma_f32_16x16x32_f16(al1, jh[0][c], aL10, 0, 0, 0);
        aL11 = __builtin_amdgcn_mfma_f32_16x16x32_f16(ah1, jl[1][c], aL11, 0, 0, 0);
        aL11 = __builtin_amdgcn_mfma_f32_16x16x32_f16(al1, jh[1][c], aL11, 0, 0, 0);
      }
      #pragma unroll
      for (int i = 0; i < 4; ++i) {
        int row = q*4 + i;                   // C/D: col=lane&15, row=quad*4+reg
        sh_C[wave][ row     *32      + r] = aH00[i] + INV_LO_SCALE*aL00[i];
        sh_C[wave][ row     *32 + 16 + r] = aH01[i] + INV_LO_SCALE*aL01[i];
        sh_C[wave][(row+16) *32      + r] = aH10[i] + INV_LO_SCALE*aL10[i];
        sh_C[wave][(row+16) *32 + 16 + r] = aH11[i] + INV_LO_SCALE*aL11[i];
      }
    }
    __syncthreads();

    // ---- h_I update (needs sh_part complete; all 4 waves contributed) ----
    if (tid < 32) {
      float s = 0.0f;
      #pragma unroll
      for (int gc = 0; gc < 8; ++gc) s += sh_part[gc*32 + tid];
      float hI = sh_hI[tid];
      sh_RI[tid] = rate_f(hI);               // pre-update R_I
      float hI2 = hI + DT_*INV_TAU*(-hI + J_IE_*s);
      sh_hI[tid] = hI2;
      if (wg == 0) __builtin_nontemporal_store(hI2, &out[HI_OFF + (size_t)t*B_ + tid]);
    }
    __syncthreads();

    // ---- phase D: h update (registers) + all_h store ----
    #pragma unroll
    for (int c = 0; c < 2; ++c) {
      const int b = bq + 16*c;
      const int e = b*32 + 2*np;
      float sy0 = sh_C[0][e]   + sh_C[1][e]   + sh_C[2][e]   + sh_C[3][e];
      float sy1 = sh_C[0][e+1] + sh_C[1][e+1] + sh_C[2][e+1] + sh_C[3][e+1];
      float ib = sh_inp[b];
      float ri = J_EI_*INV_TAU*sh_RI[b];
      float dh0 = (-hh[c][0] + sy0 + I_B_ + ib*w0)*INV_TAU - ri;
      float dh1 = (-hh[c][1] + sy1 + I_B_ + ib*w1)*INV_TAU - ri;
      hh[c][0] += dh0*DT_;
      hh[c][1] += dh1*DT_;
      f32x2 hv = {hh[c][0], hh[c][1]};
      __builtin_nontemporal_store(hv,
          (f32x2*)&out[(size_t)t*(B_*N_) + (size_t)b*N_ + n0]);
    }
    // next A reads only this thread's registers; shared buffers are re-written
    // only after the next barriers -> no extra __syncthreads needed here
  }
}

// outputs[t,b] = sum_n rate(all_h[t,b,n]) * W_out[n] — post-hoc, no atomics
__global__ __launch_bounds__(256) void out_kernel(
    const float* __restrict__ allh, const float* __restrict__ W_out,
    float* __restrict__ outp)
{
  const int bid = blockIdx.x;              // t*32 + b
  const int tid = threadIdx.x;
  __shared__ float red[4];
  const float* hrow = allh + (size_t)bid * N_;
  float s = 0.0f;
  #pragma unroll
  for (int i = 0; i < 8; ++i) {
    int n = tid + 256*i;
    s += rate_f(hrow[n]) * W_out[n];
  }
  s += __shfl_xor(s, 32); s += __shfl_xor(s, 16); s += __shfl_xor(s, 8);
  s += __shfl_xor(s, 4);  s += __shfl_xor(s, 2);  s += __shfl_xor(s, 1);
  if ((tid & 63) == 0) red[tid >> 6] = s;
  __syncthreads();
  if (tid == 0) outp[bid] = red[0] + red[1] + red[2] + red[3];
}

extern "C" void kernel_launch(void* const* d_in, const int* in_sizes, int n_in,
                              void* d_out, int out_size, void* d_ws, size_t ws_size,
                              hipStream_t stream)
{
  const float* inp   = (const float*)d_in[0];
  const float* W_in  = (const float*)d_in[1];
  const float* J     = (const float*)d_in[2];
  const float* W_out = (const float*)d_in[3];
  float* out = (float*)d_out;

  hipLaunchKernelGGL(init_kernel, dim3(1), dim3(NWG*16), 0, stream);
  hipLaunchKernelGGL(stp_kernel, dim3(NWG), dim3(256), 0, stream,
                     inp, W_in, J, out);
  hipLaunchKernelGGL(out_kernel, dim3(T_*B_), dim3(256), 0, stream,
                     out, W_out, out + OUT_OFF);
}

// Round 3
// 9665.025 us; speedup vs baseline: 1.1504x; 1.0226x over previous
//
#include <hip/hip_runtime.h>

#define N_ 2048
#define T_ 512
#define B_ 32
#define NWG 64            // 64 blocks, 1 per CU -> always co-resident (256 CUs)
#define NS 32
#define DT_ 1e-4f
#define U_CONST_ 0.3f
#define TAU_F_ 1.5f
#define TAU_D_ 0.3f
#define ALPHA_ 1.5f
#define I_B_ 8.0f
#define J_EI_ 1.1f
#define J_IE_ 2.2f
#define INV_TAU 125.0f          // 1/0.008
#define INV_ALPHA (1.0f/1.5f)
#define LO_SCALE 4096.0f        // 2^12: keeps lo parts out of fp16 denormal range
#define INV_LO_SCALE 2.44140625e-4f

// d_out float offsets: all_h, all_u, all_x, all_hI, outputs
#define U_OFF  (512ull*32*2048)
#define X_OFF  (2ull*512*32*2048)
#define HI_OFF (3ull*512*32*2048)
#define OUT_OFF (HI_OFF + 512ull*32)

typedef _Float16 half8 __attribute__((ext_vector_type(8)));
typedef float f32x4 __attribute__((ext_vector_type(4)));
typedef float f32x2 __attribute__((ext_vector_type(2)));
typedef unsigned long long u64;
typedef u64 u64x2 __attribute__((ext_vector_type(2)));

// r6 exchange model: v is STREAMED PER STEP (g_v*[t]) so every address is
// written exactly once per launch -> no stale L1/L2 line can exist -> the
// consumer side may use PLAIN CACHED loads (global_load_dwordx4, deeply
// pipelined, L2-shared by the 8 WGs of each XCD: 16MB/step of MALL-bypass
// reads becomes 2MB MALL + 14MB L2). Producers keep write-through sc0/sc1
// stores so data is at the MALL before the epoch flag is published.
// Line-span safety: a 128B line spans exactly 2 adjacent producer WGs' v
// slices; producer groups are 16-aligned, so every line a wave reads is
// fully covered by the 16 flags it waited on. g_rp lines WOULD straddle
// producer groups, so the rp gather stays on the bypass path.
__device__ u64   g_vh[T_][(B_*N_)/4];   // v hi-halves, [t][b][n] packed 4/qword (64MB)
__device__ u64   g_vl[T_][(B_*N_)/4];   // v lo-halves (pre-scaled by 2^12)     (64MB)
__device__ float g_rp[2][B_*NWG];       // R partial sums, [b][wg] (bypass-only)
__device__ unsigned g_flags[NWG*16];    // per-WG epoch flag, 64B apart

#define SYS_LD_F32(p)   __hip_atomic_load((p), __ATOMIC_RELAXED, __HIP_MEMORY_SCOPE_SYSTEM)
#define SYS_LD_U32(p)   __hip_atomic_load((p), __ATOMIC_RELAXED, __HIP_MEMORY_SCOPE_SYSTEM)
#define SYS_ST_U32(p,v) __hip_atomic_store((p), (v), __ATOMIC_RELAXED, __HIP_MEMORY_SCOPE_SYSTEM)
#define SYS_ST_F32(p,v) __hip_atomic_store((p), (v), __ATOMIC_RELAXED, __HIP_MEMORY_SCOPE_SYSTEM)

__device__ inline float rate_f(float h) {
  float z = h * INV_ALPHA;
  return ALPHA_ * (fmaxf(z, 0.0f) + log1pf(expf(-fabsf(z))));
}

// flags are monotonic within a launch; must start at 0 each launch
__global__ void init_kernel() {
  g_flags[threadIdx.x] = 0u;      // 1024 threads == NWG*16 entries
}

__global__ __launch_bounds__(256, 1) void stp_kernel(
    const float* __restrict__ inp, const float* __restrict__ W_in,
    const float* __restrict__ J, float* __restrict__ out)
{
  const int tid  = threadIdx.x;
  const int wg   = blockIdx.x;
  const int wave = tid >> 6;
  const int lane = tid & 63;

  __shared__ float sh_C[4][1024];
  __shared__ float sh_part[256];         // [gc(8)][b(32)]; gc = wave*2 + half
  __shared__ float sh_hI[32], sh_RI[32], sh_inp[32];

  // ---- J slice -> registers as split fp16 B-fragments ----
  half8 jh[2][16], jl[2][16];
  {
    const int r = lane & 15, q = lane >> 4;
    #pragma unroll
    for (int nt = 0; nt < 2; ++nt)
      #pragma unroll
      for (int c = 0; c < 16; ++c) {
        const float* src = J + (size_t)(wg*NS + nt*16 + r) * N_ + wave*512 + c*32 + q*8;
        half8 hv, lv;
        #pragma unroll
        for (int j = 0; j < 8; ++j) {
          float f = src[j];
          _Float16 hi = (_Float16)f;
          _Float16 lo = (_Float16)((f - (float)hi) * LO_SCALE);
          hv[j] = hi; lv[j] = lo;
        }
        jh[nt][c] = hv; jl[nt][c] = lv;
      }
  }

  // thread -> (2 adjacent neurons) x (2 batches); state lives in registers
  const int np = tid & 15;               // neuron-pair index within WG
  const int n0 = wg*NS + 2*np;           // global neuron (even)
  const int bq = tid >> 4;               // batch 0..15 (+16 for c=1)
  const float w0 = W_in[n0], w1 = W_in[n0+1];

  float hh[2][2], uu[2][2], xx[2][2];
  #pragma unroll
  for (int c = 0; c < 2; ++c)
    #pragma unroll
    for (int j = 0; j < 2; ++j) { hh[c][j] = 0.0f; uu[c][j] = U_CONST_; xx[c][j] = 1.0f; }

  if (tid < 32) sh_hI[tid] = 0.0f;
  __syncthreads();

  for (int t = 0; t < T_; ++t) {
    const int pb = t & 1;
    unsigned* vhd = (unsigned*)g_vh[t];
    unsigned* vld = (unsigned*)g_vl[t];

    // ---- phase A: R, v (split fp16, write-through stores), u/x update, R-partials ----
    #pragma unroll
    for (int c = 0; c < 2; ++c) {
      const int b = bq + 16*c;
      float R0 = rate_f(hh[c][0]), R1 = rate_f(hh[c][1]);
      float v0 = uu[c][0]*xx[c][0]*R0, v1 = uu[c][1]*xx[c][1]*R1;
      _Float16 h0 = (_Float16)v0, h1 = (_Float16)v1;
      _Float16 l0 = (_Float16)((v0 - (float)h0) * LO_SCALE);
      _Float16 l1 = (_Float16)((v1 - (float)h1) * LO_SCALE);
      unsigned hp = (unsigned)__builtin_bit_cast(unsigned short, h0)
                  | ((unsigned)__builtin_bit_cast(unsigned short, h1) << 16);
      unsigned lp = (unsigned)__builtin_bit_cast(unsigned short, l0)
                  | ((unsigned)__builtin_bit_cast(unsigned short, l1) << 16);
      const unsigned idx = (unsigned)(b*N_ + n0) >> 1;
      SYS_ST_U32(vhd + idx, hp);
      SYS_ST_U32(vld + idx, lp);
      uu[c][0] += ((U_CONST_-uu[c][0])*(1.0f/TAU_F_) + U_CONST_*(1.0f-uu[c][0])*R0)*DT_;
      uu[c][1] += ((U_CONST_-uu[c][1])*(1.0f/TAU_F_) + U_CONST_*(1.0f-uu[c][1])*R1)*DT_;
      xx[c][0] += ((1.0f-xx[c][0])*(1.0f/TAU_D_) - v0)*DT_;
      xx[c][1] += ((1.0f-xx[c][1])*(1.0f/TAU_D_) - v1)*DT_;
      // WG-complete R sum for batch b lives in this 16-lane group
      float s = R0 + R1;
      s += __shfl_xor(s, 1); s += __shfl_xor(s, 2);
      s += __shfl_xor(s, 4); s += __shfl_xor(s, 8);
      if ((lane & 15) == 0) SYS_ST_F32(&g_rp[pb][b*NWG + wg], s);
    }

    // ---- arrive: drain all waves' write-through stores, then publish epoch ----
    __syncthreads();                     // per-wave vmcnt(0): stores are at the MALL
    if (tid == 0) SYS_ST_U32(&g_flags[wg*16], (unsigned)(t + 1));

    // overlapped: output stores (nontemporal, never re-read by this kernel)
    #pragma unroll
    for (int c = 0; c < 2; ++c) {
      const int b = bq + 16*c;
      const size_t o = (size_t)t*(B_*N_) + (size_t)b*N_ + n0;
      f32x2 uv = {uu[c][0], uu[c][1]};
      f32x2 xv = {xx[c][0], xx[c][1]};
      __builtin_nontemporal_store(uv, (f32x2*)&out[U_OFF + o]);
      __builtin_nontemporal_store(xv, (f32x2*)&out[X_OFF + o]);
    }
    if (tid < 32) sh_inp[tid] = inp[t*B_ + tid];

    // ---- per-wave wait: only this wave's 16 producers (WGs 16*wave .. +15) ----
    {
      const unsigned target = (unsigned)(t + 1);
      const int p = wave*16 + (lane & 15);
      while (true) {
        unsigned f = SYS_LD_U32(&g_flags[p*16]);
        if (__ballot(f >= target) == ~0ull) break;
        __builtin_amdgcn_s_sleep(1);
      }
    }
    __atomic_signal_fence(__ATOMIC_ACQUIRE);

    // ---- per-wave R-partial gather (bypass loads; lines straddle groups) ----
    {
      const int b2 = lane & 31, half = lane >> 5;
      float s = 0.0f;
      #pragma unroll
      for (int k = 0; k < 8; ++k)
        s += SYS_LD_F32(&g_rp[pb][b2*NWG + wave*16 + half*8 + k]);
      sh_part[(wave*2 + half)*32 + b2] = s;
    }

    // ---- phase C: split-fp16 MFMA; v via PLAIN CACHED dwordx4 loads ----
    // (addresses are step-unique -> no staleness; 8 WGs/XCD share L2 fills)
    {
      const int r = lane & 15, q = lane >> 4;
      const u64* vhp = g_vh[t];
      const u64* vlp = g_vl[t];
      f32x4 aH00 = {0,0,0,0}, aH01 = {0,0,0,0}, aH10 = {0,0,0,0}, aH11 = {0,0,0,0};
      f32x4 aL00 = {0,0,0,0}, aL01 = {0,0,0,0}, aL10 = {0,0,0,0}, aL11 = {0,0,0,0};
      const int base0 = (r*N_      + wave*512 + q*8) >> 2;   // qword index
      const int base1 = ((r+16)*N_ + wave*512 + q*8) >> 2;
      #pragma unroll
      for (int c = 0; c < 16; ++c) {
        const int o0 = base0 + c*8, o1 = base1 + c*8;
        u64x2 th0 = *(const u64x2*)(vhp + o0);
        u64x2 tl0 = *(const u64x2*)(vlp + o0);
        u64x2 th1 = *(const u64x2*)(vhp + o1);
        u64x2 tl1 = *(const u64x2*)(vlp + o1);
        half8 ah0 = __builtin_bit_cast(half8, th0);
        half8 al0 = __builtin_bit_cast(half8, tl0);
        half8 ah1 = __builtin_bit_cast(half8, th1);
        half8 al1 = __builtin_bit_cast(half8, tl1);
        aH00 = __builtin_amdgcn_mfma_f32_16x16x32_f16(ah0, jh[0][c], aH00, 0, 0, 0);
        aH01 = __builtin_amdgcn_mfma_f32_16x16x32_f16(ah0, jh[1][c], aH01, 0, 0, 0);
        aH10 = __builtin_amdgcn_mfma_f32_16x16x32_f16(ah1, jh[0][c], aH10, 0, 0, 0);
        aH11 = __builtin_amdgcn_mfma_f32_16x16x32_f16(ah1, jh[1][c], aH11, 0, 0, 0);
        aL00 = __builtin_amdgcn_mfma_f32_16x16x32_f16(ah0, jl[0][c], aL00, 0, 0, 0);
        aL00 = __builtin_amdgcn_mfma_f32_16x16x32_f16(al0, jh[0][c], aL00, 0, 0, 0);
        aL01 = __builtin_amdgcn_mfma_f32_16x16x32_f16(ah0, jl[1][c], aL01, 0, 0, 0);
        aL01 = __builtin_amdgcn_mfma_f32_16x16x32_f16(al0, jh[1][c], aL01, 0, 0, 0);
        aL10 = __builtin_amdgcn_mfma_f32_16x16x32_f16(ah1, jl[0][c], aL10, 0, 0, 0);
        aL10 = __builtin_amdgcn_mfma_f32_16x16x32_f16(al1, jh[0][c], aL10, 0, 0, 0);
        aL11 = __builtin_amdgcn_mfma_f32_16x16x32_f16(ah1, jl[1][c], aL11, 0, 0, 0);
        aL11 = __builtin_amdgcn_mfma_f32_16x16x32_f16(al1, jh[1][c], aL11, 0, 0, 0);
      }
      #pragma unroll
      for (int i = 0; i < 4; ++i) {
        int row = q*4 + i;                   // C/D: col=lane&15, row=quad*4+reg
        sh_C[wave][ row     *32      + r] = aH00[i] + INV_LO_SCALE*aL00[i];
        sh_C[wave][ row     *32 + 16 + r] = aH01[i] + INV_LO_SCALE*aL01[i];
        sh_C[wave][(row+16) *32      + r] = aH10[i] + INV_LO_SCALE*aL10[i];
        sh_C[wave][(row+16) *32 + 16 + r] = aH11[i] + INV_LO_SCALE*aL11[i];
      }
    }
    __syncthreads();

    // ---- h_I update (needs sh_part complete; all 4 waves contributed) ----
    if (tid < 32) {
      float s = 0.0f;
      #pragma unroll
      for (int gc = 0; gc < 8; ++gc) s += sh_part[gc*32 + tid];
      float hI = sh_hI[tid];
      sh_RI[tid] = rate_f(hI);               // pre-update R_I
      float hI2 = hI + DT_*INV_TAU*(-hI + J_IE_*s);
      sh_hI[tid] = hI2;
      if (wg == 0) __builtin_nontemporal_store(hI2, &out[HI_OFF + (size_t)t*B_ + tid]);
    }
    __syncthreads();

    // ---- phase D: h update (registers) + all_h store ----
    #pragma unroll
    for (int c = 0; c < 2; ++c) {
      const int b = bq + 16*c;
      const int e = b*32 + 2*np;
      float sy0 = sh_C[0][e]   + sh_C[1][e]   + sh_C[2][e]   + sh_C[3][e];
      float sy1 = sh_C[0][e+1] + sh_C[1][e+1] + sh_C[2][e+1] + sh_C[3][e+1];
      float ib = sh_inp[b];
      float ri = J_EI_*INV_TAU*sh_RI[b];
      float dh0 = (-hh[c][0] + sy0 + I_B_ + ib*w0)*INV_TAU - ri;
      float dh1 = (-hh[c][1] + sy1 + I_B_ + ib*w1)*INV_TAU - ri;
      hh[c][0] += dh0*DT_;
      hh[c][1] += dh1*DT_;
      f32x2 hv = {hh[c][0], hh[c][1]};
      __builtin_nontemporal_store(hv,
          (f32x2*)&out[(size_t)t*(B_*N_) + (size_t)b*N_ + n0]);
    }
    // next A reads only this thread's registers; shared buffers are re-written
    // only after the next barriers -> no extra __syncthreads needed here
  }
}

// outputs[t,b] = sum_n rate(all_h[t,b,n]) * W_out[n] — post-hoc, no atomics
__global__ __launch_bounds__(256) void out_kernel(
    const float* __restrict__ allh, const float* __restrict__ W_out,
    float* __restrict__ outp)
{
  const int bid = blockIdx.x;              // t*32 + b
  const int tid = threadIdx.x;
  __shared__ float red[4];
  const float* hrow = allh + (size_t)bid * N_;
  float s = 0.0f;
  #pragma unroll
  for (int i = 0; i < 8; ++i) {
    int n = tid + 256*i;
    s += rate_f(hrow[n]) * W_out[n];
  }
  s += __shfl_xor(s, 32); s += __shfl_xor(s, 16); s += __shfl_xor(s, 8);
  s += __shfl_xor(s, 4);  s += __shfl_xor(s, 2);  s += __shfl_xor(s, 1);
  if ((tid & 63) == 0) red[tid >> 6] = s;
  __syncthreads();
  if (tid == 0) outp[bid] = red[0] + red[1] + red[2] + red[3];
}

extern "C" void kernel_launch(void* const* d_in, const int* in_sizes, int n_in,
                              void* d_out, int out_size, void* d_ws, size_t ws_size,
                              hipStream_t stream)
{
  const float* inp   = (const float*)d_in[0];
  const float* W_in  = (const float*)d_in[1];
  const float* J     = (const float*)d_in[2];
  const float* W_out = (const float*)d_in[3];
  float* out = (float*)d_out;

  hipLaunchKernelGGL(init_kernel, dim3(1), dim3(NWG*16), 0, stream);
  hipLaunchKernelGGL(stp_kernel, dim3(NWG), dim3(256), 0, stream,
                     inp, W_in, J, out);
  hipLaunchKernelGGL(out_kernel, dim3(T_*B_), dim3(256), 0, stream,
                     out, W_out, out + OUT_OFF);
}